// Round 3
// baseline (8041.145 us; speedup 1.0000x reference)
//
#include <hip/hip_runtime.h>
#include <hip/hip_bf16.h>
#include <math.h>

// Problem constants
#define A_DIM 1024      // NB_ATOMS
#define D_DIM 768       // 3*16*16
#define B_DIM 16384     // BATCH
#define TEMP_C 100.0f
#define EPS_C 1e-8f

// Round 9 = round-8 (audited, still unbenched due to broker timeouts) plus
// shuffle-based block reductions (zero-blast-radius change set):
//  - block_reduce_sum/max: 8-barrier LDS tree -> wave shfl_xor (6 steps) +
//    4-element LDS combine (2 barriers). stats_kernel uses a fused 3-way
//    variant (one barrier pair for all three sums).
//  - ALL MFMA kernels, epilogues, reset ordering byte-identical to round 8:
//    * cq fused into fused_grad epilogue (ndupdate no longer streams qt)
//    * per-iter init/cq0 dispatches eliminated (resets piggybacked)
//  Workspace ~196 MiB unchanged.

typedef __attribute__((ext_vector_type(8))) short short8;
typedef __attribute__((ext_vector_type(4))) float f32x4;
#define MFMA16(a, b, c) __builtin_amdgcn_mfma_f32_16x16x32_bf16(a, b, c, 0, 0, 0)

typedef __attribute__((address_space(3))) unsigned char lds_byte;
typedef __attribute__((address_space(1))) const unsigned char g_byte;
__device__ __forceinline__ void async_copy16(const void* gptr, void* lptr) {
    __builtin_amdgcn_global_load_lds((g_byte*)gptr, (lds_byte*)lptr, 16, 0, 0);
}

// XCD-slab swizzle for 1024-block GEMM grids (assumes dispatch ~ id%8 -> XCD):
// xcd k owns m-blocks [16k,16k+16); within a slab, n is fastest so the 128-row
// Chi/Clo slice stays hot across the 8 n-tiles.
__device__ __forceinline__ void swz(int i, int& m0, int& n0) {
    int xcd = i & 7, j = i >> 3;
    m0 = ((xcd << 4) + (j >> 3)) << 7;
    n0 = (j & 7) << 7;
}

// ---------------- reductions (wave shuffle + tiny LDS combine) ----------------

__device__ __forceinline__ float wave_sum(float v) {
#pragma unroll
    for (int m = 1; m < 64; m <<= 1) v += __shfl_xor(v, m);
    return v;
}
__device__ __forceinline__ float wave_max(float v) {
#pragma unroll
    for (int m = 1; m < 64; m <<= 1) v = fmaxf(v, __shfl_xor(v, m));
    return v;
}

// red must hold >= 12 floats; 256-thread blocks (4 waves)
__device__ __forceinline__ float block_reduce_sum(float v, float* red) {
    int t = threadIdx.x;
    v = wave_sum(v);
    if ((t & 63) == 0) red[t >> 6] = v;
    __syncthreads();
    float r = red[0] + red[1] + red[2] + red[3];
    __syncthreads();
    return r;
}

__device__ __forceinline__ float block_reduce_max(float v, float* red) {
    int t = threadIdx.x;
    v = wave_max(v);
    if ((t & 63) == 0) red[t >> 6] = v;
    __syncthreads();
    float r = fmaxf(fmaxf(red[0], red[1]), fmaxf(red[2], red[3]));
    __syncthreads();
    return r;
}

// fused 3-way sum (single barrier pair) for stats_kernel
__device__ __forceinline__ void block_reduce_sum3(float& a, float& b, float& c, float* red) {
    int t = threadIdx.x;
    a = wave_sum(a);
    b = wave_sum(b);
    c = wave_sum(c);
    if ((t & 63) == 0) {
        int w = t >> 6;
        red[w] = a; red[4 + w] = b; red[8 + w] = c;
    }
    __syncthreads();
    a = red[0] + red[1] + red[2] + red[3];
    b = red[4] + red[5] + red[6] + red[7];
    c = red[8] + red[9] + red[10] + red[11];
    __syncthreads();
}

// ---------------- small helpers ----------------

__device__ __forceinline__ unsigned int fkey(float v) {
    unsigned int u = __float_as_uint(v);
    return u ^ ((u & 0x80000000u) ? 0xFFFFFFFFu : 0x80000000u);
}

__device__ __forceinline__ unsigned short f2bf(float x) {
    unsigned int u = __float_as_uint(x);
    return (unsigned short)((u + 0x7FFFu + ((u >> 16) & 1u)) >> 16);
}
__device__ __forceinline__ float bf2f(unsigned short h) {
    return __uint_as_float(((unsigned int)h) << 16);
}
__device__ __forceinline__ void split2(float x, unsigned short& hi, unsigned short& lo) {
    hi = f2bf(x);
    lo = f2bf(x - bf2f(hi));
}

// ---------------- MFMA building blocks ----------------

__device__ __forceinline__ void stage_tile8(const unsigned short* gsrc, int stride, int k0,
                                            unsigned short* ltile, int lane) {
    int srow = lane >> 2;
    int scol = (lane & 3) * 8;
#pragma unroll
    for (int s = 0; s < 8; s++) {
        const unsigned short* src = gsrc + (size_t)(s * 16 + srow) * stride + k0 + scol;
        async_copy16(src, ltile + s * 512);
    }
}

// 3-product (pair x pair) K=32 step
__device__ __forceinline__ void mfma_k32(const unsigned short* lds, int wm, int wn, int lane,
                                         f32x4 acc[4][4]) {
    int frow = lane & 15, fk = (lane >> 4) * 8;
    short8 ah[4], al[4], bh[4], bl[4];
#pragma unroll
    for (int t = 0; t < 4; t++) {
        int ar = (wm * 64 + t * 16 + frow) * 32 + fk;
        ah[t] = *(const short8*)&lds[ar];
        al[t] = *(const short8*)&lds[4096 + ar];
        int br = (wn * 64 + t * 16 + frow) * 32 + fk;
        bh[t] = *(const short8*)&lds[8192 + br];
        bl[t] = *(const short8*)&lds[12288 + br];
    }
#pragma unroll
    for (int i = 0; i < 4; i++)
#pragma unroll
        for (int j = 0; j < 4; j++) {
            acc[i][j] = MFMA16(ah[i], bh[j], acc[i][j]);
            acc[i][j] = MFMA16(ah[i], bl[j], acc[i][j]);
            acc[i][j] = MFMA16(al[i], bh[j], acc[i][j]);
        }
}

// 2-product (single-A x pair-B) K=32 step
__device__ __forceinline__ void mfma_k32_2p(const unsigned short* lds, int wm, int wn, int lane,
                                            f32x4 acc[4][4]) {
    int frow = lane & 15, fk = (lane >> 4) * 8;
    short8 ah[4], bh[4], bl[4];
#pragma unroll
    for (int t = 0; t < 4; t++) {
        int ar = (wm * 64 + t * 16 + frow) * 32 + fk;
        ah[t] = *(const short8*)&lds[ar];
        int br = (wn * 64 + t * 16 + frow) * 32 + fk;
        bh[t] = *(const short8*)&lds[8192 + br];
        bl[t] = *(const short8*)&lds[12288 + br];
    }
#pragma unroll
    for (int i = 0; i < 4; i++)
#pragma unroll
        for (int j = 0; j < 4; j++) {
            acc[i][j] = MFMA16(ah[i], bh[j], acc[i][j]);
            acc[i][j] = MFMA16(ah[i], bl[j], acc[i][j]);
        }
}

// ---------------- setup kernels ----------------

__global__ __launch_bounds__(256) void ynorm_kernel(const float* __restrict__ y,
                                                    float* __restrict__ ynorm) {
    __shared__ float red[16];
    int b = blockIdx.x;
    const float* row = y + (size_t)b * D_DIM;
    float s = 0.f;
    for (int i = threadIdx.x; i < D_DIM; i += 256) s += fabsf(row[i]);
    float tot = block_reduce_sum(s, red);
    if (threadIdx.x == 0) ynorm[b] = tot;
}

// Ynh/Ynl = split(y/ynorm)
__global__ __launch_bounds__(256) void yn_split_kernel(const float* __restrict__ y,
                                                       const float* __restrict__ ynorm,
                                                       unsigned short* __restrict__ Ynh,
                                                       unsigned short* __restrict__ Ynl) {
    int b = blockIdx.x;
    float inv = 1.f / ynorm[b];
    const float* row = y + (size_t)b * D_DIM;
    unsigned short* oh = Ynh + (size_t)b * D_DIM;
    unsigned short* ol = Ynl + (size_t)b * D_DIM;
    for (int i = threadIdx.x; i < D_DIM; i += 256) {
        unsigned short h, l;
        split2(row[i] * inv, h, l);
        oh[i] = h; ol[i] = l;
    }
}

__global__ __launch_bounds__(256) void anorm_kernel(const float* __restrict__ atoms,
                                                    float* __restrict__ an,
                                                    float* __restrict__ anrm,
                                                    unsigned short* __restrict__ Anh,
                                                    unsigned short* __restrict__ Anl) {
    __shared__ float red[16];
    int a = blockIdx.x;
    const float* row = atoms + (size_t)a * D_DIM;
    float s = 0.f;
    for (int i = threadIdx.x; i < D_DIM; i += 256) s += fabsf(row[i]);
    float tot = block_reduce_sum(s, red);
    float inv = 1.f / tot;
    for (int i = threadIdx.x; i < D_DIM; i += 256) {
        float v = row[i] * inv;
        an[(size_t)a * D_DIM + i] = v;
        unsigned short h, l;
        split2(v, h, l);
        Anh[(size_t)a * D_DIM + i] = h;
        Anl[(size_t)a * D_DIM + i] = l;
    }
    if (threadIdx.x == 0) anrm[a] = tot;
}

__global__ __launch_bounds__(256) void atrans_split_kernel(const float* __restrict__ atoms,
                                                           const float* __restrict__ anrm,
                                                           unsigned short* __restrict__ AnTh,
                                                           unsigned short* __restrict__ AnTl) {
    int n = blockIdx.x;
    for (int k = threadIdx.x; k < A_DIM; k += 256) {
        float v = atoms[(size_t)k * D_DIM + n] / anrm[k];
        unsigned short h, l;
        split2(v, h, l);
        AnTh[(size_t)n * A_DIM + k] = h;
        AnTl[(size_t)n * A_DIM + k] = l;
    }
}

__global__ __launch_bounds__(256) void split_kernel(const float* __restrict__ src,
                                                    unsigned short* __restrict__ hi,
                                                    unsigned short* __restrict__ lo,
                                                    int n4) {
    int i = blockIdx.x * 256 + threadIdx.x;
    if (i < n4) {
        float4 v = ((const float4*)src)[i];
        ushort4 h, l;
        split2(v.x, h.x, l.x);
        split2(v.y, h.y, l.y);
        split2(v.z, h.z, l.z);
        split2(v.w, h.w, l.w);
        ((ushort4*)hi)[i] = h;
        ((ushort4*)lo)[i] = l;
    }
}

__global__ __launch_bounds__(256) void fill_pair_kernel(unsigned short* __restrict__ Chi,
                                                        unsigned short* __restrict__ Clo,
                                                        size_t n4) {
    size_t i = (size_t)blockIdx.x * 256 + threadIdx.x;
    if (i < n4) {
        unsigned short h, l;
        split2(1.f / A_DIM, h, l);
        ((ushort4*)Chi)[i] = make_ushort4(h, h, h, h);
        ((ushort4*)Clo)[i] = make_ushort4(l, l, l, l);
    }
}

// fp32 vector GEMM, B transposed, setup only: X = an @ an^T
__global__ __launch_bounds__(256) void gemm_xt(const float* __restrict__ Aop,
                                               float* __restrict__ Cout) {
    const int LDT = 132;
    const int N = A_DIM, K = D_DIM;
    __shared__ float As[16 * LDT];
    __shared__ float Bs[16 * LDT];
    int m0 = blockIdx.y * 128, n0 = blockIdx.x * 128;
    int tid = threadIdx.x;
    int tx = tid & 15, ty = tid >> 4;
    float acc[8][8];
#pragma unroll
    for (int i = 0; i < 8; i++)
#pragma unroll
        for (int j = 0; j < 8; j++) acc[i][j] = 0.f;
    for (int k0 = 0; k0 < K; k0 += 16) {
#pragma unroll
        for (int s = 0; s < 2; s++) {
            int idx = tid + s * 256;
            int row = idx >> 2, kq = (idx & 3) * 4;
            float4 v = *(const float4*)(Aop + (size_t)(m0 + row) * K + k0 + kq);
            As[(kq + 0) * LDT + row] = v.x;
            As[(kq + 1) * LDT + row] = v.y;
            As[(kq + 2) * LDT + row] = v.z;
            As[(kq + 3) * LDT + row] = v.w;
        }
#pragma unroll
        for (int s = 0; s < 2; s++) {
            int idx = tid + s * 256;
            int row = idx >> 2, kq = (idx & 3) * 4;
            float4 v = *(const float4*)(Aop + (size_t)(n0 + row) * K + k0 + kq);
            Bs[(kq + 0) * LDT + row] = v.x;
            Bs[(kq + 1) * LDT + row] = v.y;
            Bs[(kq + 2) * LDT + row] = v.z;
            Bs[(kq + 3) * LDT + row] = v.w;
        }
        __syncthreads();
#pragma unroll
        for (int kk = 0; kk < 16; kk++) {
            float a[8], b[8];
            *(float4*)(a)     = *(const float4*)(As + kk * LDT + ty * 8);
            *(float4*)(a + 4) = *(const float4*)(As + kk * LDT + ty * 8 + 4);
            *(float4*)(b)     = *(const float4*)(Bs + kk * LDT + tx * 8);
            *(float4*)(b + 4) = *(const float4*)(Bs + kk * LDT + tx * 8 + 4);
#pragma unroll
            for (int i = 0; i < 8; i++)
#pragma unroll
                for (int j = 0; j < 8; j++) acc[i][j] = fmaf(a[i], b[j], acc[i][j]);
        }
        __syncthreads();
    }
#pragma unroll
    for (int i = 0; i < 8; i++) {
        int row = m0 + ty * 8 + i;
#pragma unroll
        for (int j = 0; j < 8; j += 4) {
            int col = n0 + tx * 8 + j;
            float4 v = make_float4(acc[i][j], acc[i][j + 1], acc[i][j + 2], acc[i][j + 3]);
            *(float4*)(Cout + (size_t)row * N + col) = v;
        }
    }
}

// qt = Yn @ An^T  (bf16x2 pair-pair MFMA, K=768), swizzled 1D grid of 1024
__global__ __launch_bounds__(256) void qt_mfma(const unsigned short* __restrict__ Ynh,
                                               const unsigned short* __restrict__ Ynl,
                                               const unsigned short* __restrict__ Anh,
                                               const unsigned short* __restrict__ Anl,
                                               float* __restrict__ qt) {
    __shared__ unsigned short lds[16384];
    int tid = threadIdx.x;
    int w = tid >> 6, lane = tid & 63;
    int wm = w >> 1, wn = w & 1;
    int m0, n0;
    swz(blockIdx.x, m0, n0);

    f32x4 acc[4][4];
#pragma unroll
    for (int i = 0; i < 4; i++)
#pragma unroll
        for (int j = 0; j < 4; j++) acc[i][j] = f32x4{0.f, 0.f, 0.f, 0.f};

    const unsigned short* gsrc;
    if (w == 0) gsrc = Ynh + (size_t)m0 * D_DIM;
    else if (w == 1) gsrc = Ynl + (size_t)m0 * D_DIM;
    else if (w == 2) gsrc = Anh + (size_t)n0 * D_DIM;
    else gsrc = Anl + (size_t)n0 * D_DIM;
    unsigned short* ltile = lds + w * 4096;
    for (int k0 = 0; k0 < D_DIM; k0 += 32) {
        stage_tile8(gsrc, D_DIM, k0, ltile, lane);
        __syncthreads();
        mfma_k32(lds, wm, wn, lane, acc);
        __syncthreads();
    }

    int crow = (lane >> 4) * 4, ccol = lane & 15;
#pragma unroll
    for (int i = 0; i < 4; i++) {
        int gm = m0 + wm * 64 + i * 16 + crow;
#pragma unroll
        for (int j = 0; j < 4; j++) {
            int gn = n0 + wn * 64 + j * 16 + ccol;
#pragma unroll
            for (int r = 0; r < 4; r++)
                qt[(size_t)(gm + r) * A_DIM + gn] = acc[i][j][r];
        }
    }
}

// ---------------- nondiff per-iteration kernels ----------------

// one-time init before the nondiff loop: zero keys / num_amg / cxc / cq / scal
__global__ __launch_bounds__(256) void init_kernel(unsigned long long* __restrict__ keys,
                                                   float* __restrict__ num_amg,
                                                   float* __restrict__ cxc,
                                                   float* __restrict__ cq,
                                                   float* __restrict__ scal) {
    int i = blockIdx.x * 256 + threadIdx.x;
    num_amg[i] = 0.f;
    cxc[i] = 0.f;
    cq[i] = 0.f;
    if (i < A_DIM) keys[i] = ~0ULL;
    if (i < 4) scal[i] = 0.f;
}

// nondiff fused GEMM: acc = split(c)@split(X) (K=1024, 3 products).
// Epilogue (single merged pass over the 128x128 output tile, qt read ONCE):
//   per-row c.(Xc) partials -> cxc[b]; per-row c.q partials -> cq[b];
//   column argmin of g = acc - qt -> keys.
// Also resets scal[0..3] (block 0) for this iteration's stats atomics
// (kernel-boundary ordered: prev ndupdate read scal; stats adds after us).
__global__ __launch_bounds__(256) void fused_grad(const unsigned short* __restrict__ Chi,
                                                  const unsigned short* __restrict__ Clo,
                                                  const unsigned short* __restrict__ Xhi,
                                                  const unsigned short* __restrict__ Xlo,
                                                  const float* __restrict__ qt,
                                                  unsigned long long* __restrict__ keys,
                                                  float* __restrict__ cxc,
                                                  float* __restrict__ cq,
                                                  float* __restrict__ scal) {
    __shared__ unsigned short lds[16384];
    int tid = threadIdx.x;
    if (blockIdx.x == 0 && tid < 4) scal[tid] = 0.f;
    int w = tid >> 6, lane = tid & 63;
    int wm = w >> 1, wn = w & 1;
    int m0, n0;
    swz(blockIdx.x, m0, n0);

    f32x4 acc[4][4];
#pragma unroll
    for (int i = 0; i < 4; i++)
#pragma unroll
        for (int j = 0; j < 4; j++) acc[i][j] = f32x4{0.f, 0.f, 0.f, 0.f};

    const unsigned short* gsrc;
    if (w == 0) gsrc = Chi + (size_t)m0 * A_DIM;
    else if (w == 1) gsrc = Clo + (size_t)m0 * A_DIM;
    else if (w == 2) gsrc = Xhi + (size_t)n0 * A_DIM;
    else gsrc = Xlo + (size_t)n0 * A_DIM;
    unsigned short* ltile = lds + w * 4096;
    for (int k0 = 0; k0 < A_DIM; k0 += 32) {
        stage_tile8(gsrc, A_DIM, k0, ltile, lane);
        __syncthreads();
        mfma_k32(lds, wm, wn, lane, acc);
        __syncthreads();
    }

    int crow = (lane >> 4) * 4, ccol = lane & 15;
    unsigned long long best[4] = {~0ULL, ~0ULL, ~0ULL, ~0ULL};

    // merged epilogue: cxc/cq row partials + per-column argmin, one qt pass
#pragma unroll
    for (int i = 0; i < 4; i++)
#pragma unroll
        for (int r = 0; r < 4; r++) {
            int gm = m0 + wm * 64 + i * 16 + crow + r;
            float pcx = 0.f, pcq = 0.f;
#pragma unroll
            for (int j = 0; j < 4; j++) {
                int gn = n0 + wn * 64 + j * 16 + ccol;
                size_t idx = (size_t)gm * A_DIM + gn;
                float c = bf2f(Chi[idx]) + bf2f(Clo[idx]);
                float q = qt[idx];
                float xc = acc[i][j][r];
                pcx += c * xc;
                pcq += c * q;
                unsigned long long key =
                    ((unsigned long long)fkey(xc - q) << 32) | (unsigned int)gm;
                if (key < best[j]) best[j] = key;
            }
            for (int mm = 1; mm < 16; mm <<= 1) {
                pcx += __shfl_xor(pcx, mm, 16);
                pcq += __shfl_xor(pcq, mm, 16);
            }
            if (ccol == 0) {
                atomicAdd(&cxc[gm], pcx);
                atomicAdd(&cq[gm], pcq);
            }
        }

#pragma unroll
    for (int j = 0; j < 4; j++) {
        int gn = n0 + wn * 64 + j * 16 + ccol;
        unsigned long long o = __shfl_xor(best[j], 16);
        if (o < best[j]) best[j] = o;
        o = __shfl_xor(best[j], 32);
        if (o < best[j]) best[j] = o;
        if ((lane >> 4) == 0) atomicMin(&keys[gn], best[j]);
    }
}

// merged stats. Block per atom a:
//   ba = keys[a].low; bstar[a] = ba
//   scal0 += sum_{i: keys[i].low==ba} Xf[a,i]          (pairs)
//   xc = Xf[a,:] . c[ba,:] (fp32-exact);  scal2 += xc; num_amg[ba] += xc - qt[ba,a]
//   scal1 += sum of cxc[16a .. 16a+16)                 (Sum_b c.Xc)
__global__ __launch_bounds__(256) void stats_kernel(const float* __restrict__ Xf,
                                                    const unsigned long long* __restrict__ keys,
                                                    const unsigned short* __restrict__ Chi,
                                                    const unsigned short* __restrict__ Clo,
                                                    const float* __restrict__ qt,
                                                    const float* __restrict__ cxc,
                                                    int* __restrict__ bstar,
                                                    float* __restrict__ num_amg,
                                                    float* __restrict__ scal) {
    __shared__ float red[16];
    int a = blockIdx.x;
    int ba = (int)(unsigned int)(keys[a] & 0xFFFFFFFFULL);
    const float* xr = Xf + (size_t)a * A_DIM;
    const unsigned short* ch = Chi + (size_t)ba * A_DIM;
    const unsigned short* cl = Clo + (size_t)ba * A_DIM;
    float ps = 0.f, xs = 0.f;
    for (int i = threadIdx.x; i < A_DIM; i += 256) {
        float xv = xr[i];
        if ((int)(unsigned int)(keys[i] & 0xFFFFFFFFULL) == ba) ps += xv;
        xs += xv * (bf2f(ch[i]) + bf2f(cl[i]));
    }
    float s1p = (threadIdx.x < 16) ? cxc[(a << 4) + threadIdx.x] : 0.f;
    block_reduce_sum3(ps, xs, s1p, red);
    if (threadIdx.x == 0) {
        bstar[a] = ba;
        atomicAdd(&scal[0], ps);
        atomicAdd(&scal[2], xs);
        atomicAdd(&scal[1], s1p);
        atomicAdd(&num_amg[ba], xs - qt[(size_t)ba * A_DIM + a]);
    }
}

// nondiff update: lam = clip((cxc-cq-amg)/(scal0+scal1-2*scal2+eps));
// c' = (1-lam)c + lam*am; refresh splits.  cq/cxc come from fused_grad,
// so no qt stream and no block reduce here.  Tail resets the per-iteration
// accumulators for the NEXT iteration (per-block-owned addresses only;
// scal is NOT reset here since every block reads it -> fused_grad does that).
__global__ __launch_bounds__(256) void ndupdate_kernel(unsigned short* __restrict__ Chi,
                                                       unsigned short* __restrict__ Clo,
                                                       const int* __restrict__ bstar,
                                                       float* __restrict__ cxc,
                                                       float* __restrict__ cq,
                                                       float* __restrict__ num_amg,
                                                       const float* __restrict__ scal,
                                                       unsigned long long* __restrict__ keys) {
    int b = blockIdx.x;
    float den = scal[0] + scal[1] - 2.f * scal[2] + EPS_C;
    float lam = fminf(fmaxf((cxc[b] - cq[b] - num_amg[b]) / den, 0.f), 1.f);
    float om = 1.f - lam;
    int i = threadIdx.x;
    ushort4* h4 = (ushort4*)(Chi + (size_t)b * A_DIM);
    ushort4* l4 = (ushort4*)(Clo + (size_t)b * A_DIM);
    ushort4 h = h4[i], l = l4[i];
    int4 bs = ((const int4*)bstar)[i];
    float c0 = om * (bf2f(h.x) + bf2f(l.x)) + ((bs.x == b) ? lam : 0.f);
    float c1 = om * (bf2f(h.y) + bf2f(l.y)) + ((bs.y == b) ? lam : 0.f);
    float c2 = om * (bf2f(h.z) + bf2f(l.z)) + ((bs.z == b) ? lam : 0.f);
    float c3 = om * (bf2f(h.w) + bf2f(l.w)) + ((bs.w == b) ? lam : 0.f);
    split2(c0, h.x, l.x);
    split2(c1, h.y, l.y);
    split2(c2, h.z, l.z);
    split2(c3, h.w, l.w);
    h4[i] = h; l4[i] = l;
    __syncthreads();  // drains all reads above before the resets below
    if (i == 0) {
        cxc[b] = 0.f;
        cq[b] = 0.f;
        num_amg[b] = 0.f;
        if (b < A_DIM) keys[b] = ~0ULL;
    }
}

// ---------------- diff-phase GEMM (single-A x pair-X, 2 products) ----------------
// MODE 1: G[idx] = acc - qt[idx]            (A = c-hi)
// MODE 2: scal3 += sum(acc * recon(Chi,Clo))(A = d-hi, dot for denominator)
template <int MODE>
__global__ __launch_bounds__(256) void gemm_single(const unsigned short* __restrict__ Ahi,
                                                   const unsigned short* __restrict__ Xhi,
                                                   const unsigned short* __restrict__ Xlo,
                                                   const float* __restrict__ qt,
                                                   const unsigned short* __restrict__ Chi,
                                                   const unsigned short* __restrict__ Clo,
                                                   float* __restrict__ G,
                                                   float* __restrict__ scal3) {
    __shared__ unsigned short lds[16384];
    __shared__ float red[16];
    int tid = threadIdx.x;
    int w = tid >> 6, lane = tid & 63;
    int wm = w >> 1, wn = w & 1;
    int m0, n0;
    swz(blockIdx.x, m0, n0);

    f32x4 acc[4][4];
#pragma unroll
    for (int i = 0; i < 4; i++)
#pragma unroll
        for (int j = 0; j < 4; j++) acc[i][j] = f32x4{0.f, 0.f, 0.f, 0.f};

    const unsigned short* gsrc = nullptr;
    unsigned short* ltile = nullptr;
    if (w == 0) { gsrc = Ahi + (size_t)m0 * A_DIM; ltile = lds; }
    else if (w == 2) { gsrc = Xhi + (size_t)n0 * A_DIM; ltile = lds + 8192; }
    else if (w == 3) { gsrc = Xlo + (size_t)n0 * A_DIM; ltile = lds + 12288; }
    for (int k0 = 0; k0 < A_DIM; k0 += 32) {
        if (w != 1) stage_tile8(gsrc, A_DIM, k0, ltile, lane);
        __syncthreads();
        mfma_k32_2p(lds, wm, wn, lane, acc);
        __syncthreads();
    }

    int crow = (lane >> 4) * 4, ccol = lane & 15;
    if (MODE == 1) {
#pragma unroll
        for (int i = 0; i < 4; i++) {
            int gm = m0 + wm * 64 + i * 16 + crow;
#pragma unroll
            for (int j = 0; j < 4; j++) {
                int gn = n0 + wn * 64 + j * 16 + ccol;
#pragma unroll
                for (int r = 0; r < 4; r++) {
                    size_t idx = (size_t)(gm + r) * A_DIM + gn;
                    G[idx] = acc[i][j][r] - qt[idx];
                }
            }
        }
    } else {
        float part = 0.f;
#pragma unroll
        for (int i = 0; i < 4; i++) {
            int gm = m0 + wm * 64 + i * 16 + crow;
#pragma unroll
            for (int j = 0; j < 4; j++) {
                int gn = n0 + wn * 64 + j * 16 + ccol;
#pragma unroll
                for (int r = 0; r < 4; r++) {
                    size_t idx = (size_t)(gm + r) * A_DIM + gn;
                    float d = bf2f(Chi[idx]) + bf2f(Clo[idx]);
                    part += acc[i][j][r] * d;
                }
            }
        }
        float tot = block_reduce_sum(part, red);
        if (tid == 0) atomicAdd(scal3, tot);
    }
}

// ---------------- diff-phase small kernels ----------------

__global__ __launch_bounds__(256) void softmax_kernel(float* __restrict__ G,
                                                      unsigned short* __restrict__ Chi,
                                                      unsigned short* __restrict__ Clo,
                                                      float* __restrict__ num_cg,
                                                      float* __restrict__ scal3) {
    __shared__ float red[16];
    int b = blockIdx.x;
    int i = threadIdx.x;
    if (b == 0 && i == 0) *scal3 = 0.f;  // reset before the dot dispatch
    float4* g4 = (float4*)(G + (size_t)b * A_DIM);
    ushort4* h4 = (ushort4*)(Chi + (size_t)b * A_DIM);
    ushort4* l4 = (ushort4*)(Clo + (size_t)b * A_DIM);
    float4 g = g4[i];
    ushort4 h = h4[i], l = l4[i];
    float c0 = bf2f(h.x) + bf2f(l.x);
    float c1 = bf2f(h.y) + bf2f(l.y);
    float c2 = bf2f(h.z) + bf2f(l.z);
    float c3 = bf2f(h.w) + bf2f(l.w);
    float4 t = make_float4(-TEMP_C * g.x, -TEMP_C * g.y, -TEMP_C * g.z, -TEMP_C * g.w);
    float m = fmaxf(fmaxf(t.x, t.y), fmaxf(t.z, t.w));
    float M = block_reduce_max(m, red);
    float4 e = make_float4(expf(t.x - M), expf(t.y - M), expf(t.z - M), expf(t.w - M));
    float S = block_reduce_sum(e.x + e.y + e.z + e.w, red);
    float inv = 1.f / S;
    float4 sm = make_float4(e.x * inv, e.y * inv, e.z * inv, e.w * inv);
    float np = (c0 - sm.x) * g.x + (c1 - sm.y) * g.y + (c2 - sm.z) * g.z + (c3 - sm.w) * g.w;
    g4[i] = sm;
    split2(sm.x - c0, h.x, l.x);
    split2(sm.y - c1, h.y, l.y);
    split2(sm.z - c2, h.z, l.z);
    split2(sm.w - c3, h.w, l.w);
    h4[i] = h; l4[i] = l;
    float nt = block_reduce_sum(np, red);
    if (i == 0) num_cg[b] = nt;
}

__global__ __launch_bounds__(256) void dupdate_kernel(const float* __restrict__ G,
                                                      unsigned short* __restrict__ Chi,
                                                      unsigned short* __restrict__ Clo,
                                                      const float* __restrict__ num_cg,
                                                      const float* __restrict__ scal3) {
    int b = blockIdx.x;
    float den = *scal3 + EPS_C;
    float lam = fminf(fmaxf(num_cg[b] / den, 0.f), 1.f);
    float om = 1.f - lam;
    int i = threadIdx.x;
    const float4* g4 = (const float4*)(G + (size_t)b * A_DIM);
    ushort4* h4 = (ushort4*)(Chi + (size_t)b * A_DIM);
    ushort4* l4 = (ushort4*)(Clo + (size_t)b * A_DIM);
    float4 sm = g4[i];
    ushort4 h = h4[i], l = l4[i];
    float c0 = sm.x - om * (bf2f(h.x) + bf2f(l.x));
    float c1 = sm.y - om * (bf2f(h.y) + bf2f(l.y));
    float c2 = sm.z - om * (bf2f(h.z) + bf2f(l.z));
    float c3 = sm.w - om * (bf2f(h.w) + bf2f(l.w));
    split2(c0, h.x, l.x);
    split2(c1, h.y, l.y);
    split2(c2, h.z, l.z);
    split2(c3, h.w, l.w);
    h4[i] = h; l4[i] = l;
}

// recon: out[b, n] = (c_b . anT[:,n]) * ynorm[b]
__global__ __launch_bounds__(256) void mfma_recon(const unsigned short* __restrict__ Chi,
                                                  const unsigned short* __restrict__ Clo,
                                                  const unsigned short* __restrict__ AnTh,
                                                  const unsigned short* __restrict__ AnTl,
                                                  const float* __restrict__ ynorm,
                                                  float* __restrict__ out) {
    __shared__ unsigned short lds[16384];
    int tid = threadIdx.x;
    int w = tid >> 6, lane = tid & 63;
    int wm = w >> 1, wn = w & 1;
    int m0 = blockIdx.y * 128, n0 = blockIdx.x * 128;

    f32x4 acc[4][4];
#pragma unroll
    for (int i = 0; i < 4; i++)
#pragma unroll
        for (int j = 0; j < 4; j++) acc[i][j] = f32x4{0.f, 0.f, 0.f, 0.f};

    const unsigned short* gsrc;
    if (w == 0) gsrc = Chi + (size_t)m0 * A_DIM;
    else if (w == 1) gsrc = Clo + (size_t)m0 * A_DIM;
    else if (w == 2) gsrc = AnTh + (size_t)n0 * A_DIM;
    else gsrc = AnTl + (size_t)n0 * A_DIM;
    unsigned short* ltile = lds + w * 4096;
    for (int k0 = 0; k0 < A_DIM; k0 += 32) {
        stage_tile8(gsrc, A_DIM, k0, ltile, lane);
        __syncthreads();
        mfma_k32(lds, wm, wn, lane, acc);
        __syncthreads();
    }

    int crow = (lane >> 4) * 4, ccol = lane & 15;
#pragma unroll
    for (int i = 0; i < 4; i++) {
        int gm = m0 + wm * 64 + i * 16 + crow;
#pragma unroll
        for (int j = 0; j < 4; j++) {
            int gn = n0 + wn * 64 + j * 16 + ccol;
#pragma unroll
            for (int r = 0; r < 4; r++)
                out[(size_t)(gm + r) * D_DIM + gn] = acc[i][j][r] * ynorm[gm + r];
        }
    }
}

// ---------------- host launch ----------------

extern "C" void kernel_launch(void* const* d_in, const int* in_sizes, int n_in,
                              void* d_out, int out_size, void* d_ws, size_t ws_size,
                              hipStream_t stream) {
    const float* y = (const float*)d_in[0];      // [B, 768]
    const float* atoms = (const float*)d_in[1];  // [A, 768]
    float* out = (float*)d_out;                  // [B, 768]

    char* ws = (char*)d_ws;
    size_t off = 0;
    auto alloc = [&](size_t bytes) -> void* {
        void* p = ws + off;
        off += (bytes + 255) & ~(size_t)255;
        return p;
    };
    const size_t BA = (size_t)B_DIM * A_DIM;
    unsigned short* Chi = (unsigned short*)alloc(BA * 2);            // 32 MiB
    unsigned short* Clo = (unsigned short*)alloc(BA * 2);            // 32 MiB
    float* Greg = (float*)alloc(BA * 4);                             // 64 MiB (aliased)
    float* qt = (float*)alloc(BA * 4);                               // 64 MiB
    unsigned short* Xhi = (unsigned short*)alloc((size_t)A_DIM * A_DIM * 2);  // 2 MiB
    unsigned short* Xlo = (unsigned short*)alloc((size_t)A_DIM * A_DIM * 2);  // 2 MiB
    float* ynorm = (float*)alloc(B_DIM * 4);
    float* anrm  = (float*)alloc(A_DIM * 4);
    float* cxc   = (float*)alloc(B_DIM * 4);
    float* cq    = (float*)alloc(B_DIM * 4);
    float* num_amg = (float*)alloc(B_DIM * 4);
    float* num_cg  = (float*)alloc(B_DIM * 4);
    unsigned long long* keys = (unsigned long long*)alloc(A_DIM * 8);
    int* bstar = (int*)alloc(A_DIM * 4);
    float* scal = (float*)alloc(256);
    (void)ws_size; (void)in_sizes; (void)n_in; (void)out_size;

    // Greg aliases (floats):
    float* Xf = Greg;                                         // 4 MiB, live thru nondiff
    float* an = Greg + (size_t)A_DIM * A_DIM;                 // 3 MiB, setup only
    unsigned short* Anh = (unsigned short*)(an + (size_t)A_DIM * D_DIM);          // 1.5 MiB
    unsigned short* Anl = Anh + (size_t)A_DIM * D_DIM;                            // 1.5 MiB
    unsigned short* Ynh = Anl + (size_t)A_DIM * D_DIM;                            // 24 MiB
    unsigned short* Ynl = Ynh + (size_t)B_DIM * D_DIM;                            // 24 MiB
    float* G = Greg;                                          // diff phase (clobbers all)
    unsigned short* AnTh = (unsigned short*)Greg;             // post-diff recon
    unsigned short* AnTl = (unsigned short*)Greg + (size_t)D_DIM * A_DIM;

    // ---- setup ----
    ynorm_kernel<<<B_DIM, 256, 0, stream>>>(y, ynorm);
    yn_split_kernel<<<B_DIM, 256, 0, stream>>>(y, ynorm, Ynh, Ynl);
    anorm_kernel<<<A_DIM, 256, 0, stream>>>(atoms, an, anrm, Anh, Anl);
    gemm_xt<<<dim3(A_DIM / 128, A_DIM / 128), 256, 0, stream>>>(an, Xf);
    split_kernel<<<A_DIM * A_DIM / 4 / 256, 256, 0, stream>>>(Xf, Xhi, Xlo, A_DIM * A_DIM / 4);
    qt_mfma<<<1024, 256, 0, stream>>>(Ynh, Ynl, Anh, Anl, qt);
    fill_pair_kernel<<<(int)(BA / 4 / 256), 256, 0, stream>>>(Chi, Clo, BA / 4);
    init_kernel<<<B_DIM / 256, 256, 0, stream>>>(keys, num_amg, cxc, cq, scal);

    // ---- 30 nondiff steps (resets piggyback on fused_grad/ndupdate) ----
    for (int it = 0; it < 30; it++) {
        fused_grad<<<1024, 256, 0, stream>>>(Chi, Clo, Xhi, Xlo, qt, keys, cxc, cq, scal);
        stats_kernel<<<A_DIM, 256, 0, stream>>>(Xf, keys, Chi, Clo, qt, cxc,
                                                bstar, num_amg, scal);
        ndupdate_kernel<<<B_DIM, 256, 0, stream>>>(Chi, Clo, bstar, cxc, cq,
                                                   num_amg, scal, keys);
    }

    // ---- 10 diff steps (G clobbers Xf/setup region) ----
    for (int it = 0; it < 10; it++) {
        gemm_single<1><<<1024, 256, 0, stream>>>(Chi, Xhi, Xlo, qt,
                                                 nullptr, nullptr, G, nullptr);
        softmax_kernel<<<B_DIM, 256, 0, stream>>>(G, Chi, Clo, num_cg, &scal[3]);
        gemm_single<2><<<1024, 256, 0, stream>>>(Chi, Xhi, Xlo, nullptr,
                                                 Chi, Clo, nullptr, &scal[3]);
        dupdate_kernel<<<B_DIM, 256, 0, stream>>>(G, Chi, Clo, num_cg, &scal[3]);
    }

    // ---- recon ----
    atrans_split_kernel<<<D_DIM, 256, 0, stream>>>(atoms, anrm, AnTh, AnTl);
    mfma_recon<<<dim3(D_DIM / 128, B_DIM / 128), 256, 0, stream>>>(Chi, Clo, AnTh, AnTl,
                                                                   ynorm, out);
}